// Round 2
// baseline (184.262 us; speedup 1.0000x reference)
//
#include <hip/hip_runtime.h>
#include <stdint.h>

// ---------------------------------------------------------------------------
// HardBinaryConv, algebraic form.
//   sign(w) = 1 - 2*[w <= 0]   (reference: 2*(w>0)-1)
//   y[n,o,h,w] = scale[o] * T[n,h,w]
//              - 2*scale[o] * sum_{(i,r,s): w[o,i,r,s]<=0} x[n,i,h+r-1,w+s-1]
//   T[n,h,w]   = sum_{r,s} U[n,h+r-1,w+s-1]   (3x3 box, zero-pad)
//   U[n,h,w]   = sum_i x[n,i,h,w]             (channel sum)
// Correction set is empty for uniform*1e-3 weights but handled exactly.
// Traffic floor: read x (103 MB) + write y (103 MB) ~= 31 us at 6.7 TB/s.
// This version: TWO kernels. boxsum folded into the broadcast kernel
// (T computed per-stripe in LDS; 448 fat write-bound blocks), deleting one
// dispatch + bubble and the T intermediate.
// ---------------------------------------------------------------------------

typedef float f32x4 __attribute__((ext_vector_type(4)));

// Stage 1, role A (blocks 0..1567): per-16-channel-group partial channel sums.
// u16 layout: [n][g=16][784] f32x4 (as floats: [n][g][3136]).
// Stage 1, role B (blocks 1568..1823): scale[o] = mean|w[o]| + sparse list of
// non-positive weights (block o-1568 owns nneg[o]; no global pre-zero needed).
__global__ __launch_bounds__(256) void stage1(const float* __restrict__ x,
                                              f32x4* __restrict__ u16,
                                              const float* __restrict__ w,
                                              float* __restrict__ scale,
                                              int* __restrict__ nneg,
                                              int* __restrict__ negidx) {
    __shared__ float red[4];
    __shared__ int cnt;
    if (blockIdx.x < 1568) {
        const int id  = blockIdx.x * 256 + threadIdx.x;
        const int n   = id / 12544;          // 12544 = 16*784
        const int rem = id - n * 12544;
        const int g   = rem / 784;
        const int hw4 = rem - g * 784;
        const f32x4* xp =
            (const f32x4*)(x + (size_t)(n * 256 + g * 16) * 3136) + hw4;
        f32x4 s = {0.f, 0.f, 0.f, 0.f};
#pragma unroll
        for (int c = 0; c < 16; ++c)         // 784 f32x4 = one 3136-elem plane
            s += __builtin_nontemporal_load(xp + c * 784);
        u16[id] = s;                         // plain store: L2/L3-resident for boxout
    } else {
        const int o = blockIdx.x - 1568, i = threadIdx.x;
        if (i == 0) cnt = 0;
        __syncthreads();
        const float* wp = w + ((size_t)o * 256 + i) * 9;
        float s = 0.f;
#pragma unroll
        for (int k = 0; k < 9; ++k) {
            const float v = wp[k];
            s += fabsf(v);
            if (v <= 0.f) {                  // sign would be -1 here (rare)
                const int slot = atomicAdd(&cnt, 1);
                negidx[o * 2304 + slot] = i * 9 + k;
            }
        }
#pragma unroll
        for (int off = 32; off > 0; off >>= 1) s += __shfl_down(s, off);
        if ((i & 63) == 0) red[i >> 6] = s;
        __syncthreads();
        if (i == 0) {
            scale[o] = (red[0] + red[1] + red[2] + red[3]) * (1.0f / 2304.0f);
            nneg[o]  = cnt;
        }
    }
}

// Stage 2: fused {16-group reduce + 3x3 box filter + per-channel broadcast}.
// grid 448 = 32 n * 14 stripes of 4 output rows. Per block:
//   - reduce u16 into 6 halo rows of U in LDS        (~21.5 KB L3 reads)
//   - box-filter into T stripe (224 floats) in LDS
//   - write scale[o]*T for all 256 o                 (229 KB NT stores)
// Writes are 896 B contiguous per (o, stripe) chunk, fully coalesced.
__global__ __launch_bounds__(256) void boxout(const float* __restrict__ u16,
                                              const float* __restrict__ scale,
                                              const int* __restrict__ nneg,
                                              const int* __restrict__ negidx,
                                              const float* __restrict__ x,
                                              float* __restrict__ out) {
    __shared__ float Us[336];                // 6 rows x 56 (halo)
    __shared__ float Tls[224];               // 4 rows x 56
    __shared__ float ssc[256];
    __shared__ int   snn[256];
    const int n  = blockIdx.x / 14;
    const int h0 = (blockIdx.x - n * 14) * 4;
    const int t  = threadIdx.x;

    ssc[t] = scale[t];                       // stage per-o constants once
    snn[t] = nneg[t];

    const float* base = u16 + (size_t)n * 16 * 3136;
    for (int idx = t; idx < 336; idx += 256) {
        const int lr = idx / 56, col = idx - lr * 56;
        const int h = h0 - 1 + lr;
        float s = 0.f;
        if (h >= 0 && h < 56) {
            const float* bp = base + h * 56 + col;
#pragma unroll
            for (int g = 0; g < 16; ++g) s += bp[g * 3136];
        }
        Us[idx] = s;
    }
    __syncthreads();
    if (t < 224) {
        const int lr = t / 56, w = t - lr * 56;
        float acc = 0.f;
#pragma unroll
        for (int r = 0; r < 3; ++r) {
            const float* row = Us + (lr + r) * 56;
            if (w > 0)  acc += row[w - 1];
            acc += row[w];
            if (w < 55) acc += row[w + 1];
        }
        Tls[t] = acc;
    }
    __syncthreads();

    const float tv = (t < 224) ? Tls[t] : 0.f;
    const int lr = t / 56, w = t - lr * 56, h = h0 + lr;
    float* obase = out + (size_t)n * 256 * 3136 + h0 * 56;
    for (int o = 0; o < 256; ++o) {
        const float sc = ssc[o];
        float v = sc * tv;
        const int nn = snn[o];
        if (nn > 0) {                        // exact sparse correction (rare)
            const float c2 = 2.f * sc;
            for (int q = 0; q < nn; ++q) {
                const int iof = negidx[o * 2304 + q];
                const int i = iof / 9, rs = iof - i * 9;
                const int r = rs / 3 - 1, s2 = rs - (rs / 3) * 3 - 1;
                const int hh = h + r, ww = w + s2;
                const float xv = (hh >= 0 && hh < 56 && ww >= 0 && ww < 56)
                                     ? x[((size_t)n * 256 + i) * 3136 + hh * 56 + ww]
                                     : 0.f;
                v -= c2 * xv;
            }
        }
        if (t < 224)
            __builtin_nontemporal_store(v, obase + (size_t)o * 3136 + t);
    }
}

// ---------------------------------------------------------------------------
extern "C" void kernel_launch(void* const* d_in, const int* in_sizes, int n_in,
                              void* d_out, int out_size, void* d_ws, size_t ws_size,
                              hipStream_t stream) {
    const float* x = (const float*)d_in[0];   // (32,256,56,56) fp32, 103 MB
    const float* w = (const float*)d_in[1];   // (256,256,3,3) fp32, 2.4 MB
    float* out = (float*)d_out;               // (32,256,56,56) fp32, 103 MB

    char* ws = (char*)d_ws;
    size_t off = 0;
    float* u16 = (float*)(ws + off);          // 32*16*3136 fp32 = 6.4 MB
    off += (size_t)32 * 16 * 3136 * 4;
    float* scale = (float*)(ws + off);        // 256 fp32
    off += 256 * 4;
    int* nneg = (int*)(ws + off);             // 256 int
    off += 256 * 4;
    int* negidx = (int*)(ws + off);           // 256*2304 int = 2.4 MB

    stage1<<<dim3(1824), 256, 0, stream>>>(x, (f32x4*)u16, w, scale, nneg, negidx);
    boxout<<<dim3(448), 256, 0, stream>>>(u16, scale, nneg, negidx, x, out);
}

// Round 3
// 183.528 us; speedup vs baseline: 1.0040x; 1.0040x over previous
//
#include <hip/hip_runtime.h>
#include <stdint.h>

// ---------------------------------------------------------------------------
// HardBinaryConv, algebraic form.
//   sign(w) = 1 - 2*[w <= 0]   (reference: 2*(w>0)-1)
//   y[n,o,h,w] = scale[o] * T[n,h,w]
//              - 2*scale[o] * sum_{(i,r,s): w[o,i,r,s]<=0} x[n,i,h+r-1,w+s-1]
//   T[n,h,w]   = sum_{r,s} U[n,h+r-1,w+s-1]   (3x3 box, zero-pad)
//   U[n,h,w]   = sum_i x[n,i,h,w]             (channel sum)
// Correction set is empty for uniform*1e-3 weights but handled exactly.
// Traffic floor: read x (103 MB) + write y (103 MB) ~= 31 us at 6.7 TB/s.
// R2 lesson: the y-write stream must stay f32x4-per-lane with >=few-thousand
// waves of store parallelism. This version: 2 kernels, broadcast kernel at
// 1792 blocks x 64 o-planes, f32x4 NT stores, T stripe computed in LDS
// (4x redundant 21.5-KB halo reads, L2/L3-resident).
// ---------------------------------------------------------------------------

typedef float f32x4 __attribute__((ext_vector_type(4)));

// Stage 1, role A (blocks 0..1567): per-16-channel-group partial channel sums.
// u16 layout: [n][g=16][784] f32x4 (as floats: [n][g][3136]).
// Stage 1, role B (blocks 1568..1823): scale[o] = mean|w[o]| + sparse list of
// non-positive weights (block o-1568 owns nneg[o]; no global pre-zero needed).
__global__ __launch_bounds__(256) void stage1(const float* __restrict__ x,
                                              f32x4* __restrict__ u16,
                                              const float* __restrict__ w,
                                              float* __restrict__ scale,
                                              int* __restrict__ nneg,
                                              int* __restrict__ negidx) {
    __shared__ float red[4];
    __shared__ int cnt;
    if (blockIdx.x < 1568) {
        const int id  = blockIdx.x * 256 + threadIdx.x;
        const int n   = id / 12544;          // 12544 = 16*784
        const int rem = id - n * 12544;
        const int g   = rem / 784;
        const int hw4 = rem - g * 784;
        const f32x4* xp =
            (const f32x4*)(x + (size_t)(n * 256 + g * 16) * 3136) + hw4;
        f32x4 s = {0.f, 0.f, 0.f, 0.f};
#pragma unroll
        for (int c = 0; c < 16; ++c)         // 784 f32x4 = one 3136-elem plane
            s += __builtin_nontemporal_load(xp + c * 784);
        u16[id] = s;                         // plain store: L2/L3-resident for boxbcast
    } else {
        const int o = blockIdx.x - 1568, i = threadIdx.x;
        if (i == 0) cnt = 0;
        __syncthreads();
        const float* wp = w + ((size_t)o * 256 + i) * 9;
        float s = 0.f;
#pragma unroll
        for (int k = 0; k < 9; ++k) {
            const float v = wp[k];
            s += fabsf(v);
            if (v <= 0.f) {                  // sign would be -1 here (rare)
                const int slot = atomicAdd(&cnt, 1);
                negidx[o * 2304 + slot] = i * 9 + k;
            }
        }
#pragma unroll
        for (int off = 32; off > 0; off >>= 1) s += __shfl_down(s, off);
        if ((i & 63) == 0) red[i >> 6] = s;
        __syncthreads();
        if (i == 0) {
            scale[o] = (red[0] + red[1] + red[2] + red[3]) * (1.0f / 2304.0f);
            nneg[o]  = cnt;
        }
    }
}

// Stage 2: fused {16-group reduce + 3x3 box + 64-channel broadcast}.
// grid 1792 = 32 n * 14 stripes (4 rows) * 4 o-groups (64 o each).
// Per block: 21.5 KB halo reads (L2/L3) -> T stripe (224 f) in LDS ->
// 64 planes * 56 f32x4 NT stores (57 KB), 896 B contiguous per (o,stripe).
__global__ __launch_bounds__(256) void boxbcast(const float* __restrict__ u16,
                                                const float* __restrict__ scale,
                                                const int* __restrict__ nneg,
                                                const int* __restrict__ negidx,
                                                const float* __restrict__ x,
                                                float* __restrict__ out) {
    __shared__ float Us[336];                // 6 rows x 56 (halo)
    __shared__ float Tls[224];               // 4 rows x 56
    __shared__ float ssc[64];
    __shared__ int   snn[64];
    const int b  = blockIdx.x;
    const int og = b & 3;                    // o-group: 64 planes
    const int ns = b >> 2;
    const int n  = ns / 14;
    const int st = ns - n * 14;
    const int h0 = st * 4;
    const int t  = threadIdx.x;

    if (t < 64) {                            // stage per-o constants
        ssc[t] = scale[og * 64 + t];
        snn[t] = nneg[og * 64 + t];
    }

    const float* base = u16 + (size_t)n * 16 * 3136;
    for (int idx = t; idx < 336; idx += 256) {
        const int lr = idx / 56, col = idx - lr * 56;
        const int h = h0 - 1 + lr;
        float s = 0.f;
        if (h >= 0 && h < 56) {
            const float* bp = base + h * 56 + col;
#pragma unroll
            for (int g = 0; g < 16; ++g) s += bp[g * 3136];
        }
        Us[idx] = s;
    }
    __syncthreads();
    if (t < 224) {
        const int lr = t / 56, w = t - lr * 56;
        float acc = 0.f;
#pragma unroll
        for (int r = 0; r < 3; ++r) {
            const float* row = Us + (lr + r) * 56;
            if (w > 0)  acc += row[w - 1];
            acc += row[w];
            if (w < 55) acc += row[w + 1];
        }
        Tls[t] = acc;
    }
    __syncthreads();

    const f32x4* T4 = (const f32x4*)Tls;     // 56 f32x4 per stripe
    float* nb = out + ((size_t)n * 256 + og * 64) * 3136 + h0 * 56;
#pragma unroll
    for (int i = 0; i < 14; ++i) {           // 3584 = 64 planes * 56 f32x4
        const int u  = t + i * 256;
        const int ol = u / 56;
        const int hw4 = u - ol * 56;
        const float sc = ssc[ol];
        f32x4 v = T4[hw4] * sc;
        const int nn = snn[ol];
        if (nn > 0) {                        // exact sparse correction (rare)
            const float c2 = 2.f * sc;
            for (int q = 0; q < nn; ++q) {
                const int iof = negidx[(og * 64 + ol) * 2304 + q];
                const int ic = iof / 9, rs = iof - ic * 9;
                const int r = rs / 3 - 1, s2 = rs - (rs / 3) * 3 - 1;
                const float* xpl = x + ((size_t)n * 256 + ic) * 3136;
#pragma unroll
                for (int e = 0; e < 4; ++e) {
                    const int p = hw4 * 4 + e;
                    const int lr = p / 56, w = p - lr * 56;
                    const int hh = h0 + lr + r, ww = w + s2;
                    const float xv = (hh >= 0 && hh < 56 && ww >= 0 && ww < 56)
                                         ? xpl[hh * 56 + ww] : 0.f;
                    v[e] -= c2 * xv;
                }
            }
        }
        __builtin_nontemporal_store(v, (f32x4*)(nb + (size_t)ol * 3136) + hw4);
    }
}

// ---------------------------------------------------------------------------
extern "C" void kernel_launch(void* const* d_in, const int* in_sizes, int n_in,
                              void* d_out, int out_size, void* d_ws, size_t ws_size,
                              hipStream_t stream) {
    const float* x = (const float*)d_in[0];   // (32,256,56,56) fp32, 103 MB
    const float* w = (const float*)d_in[1];   // (256,256,3,3) fp32, 2.4 MB
    float* out = (float*)d_out;               // (32,256,56,56) fp32, 103 MB

    char* ws = (char*)d_ws;
    size_t off = 0;
    float* u16 = (float*)(ws + off);          // 32*16*3136 fp32 = 6.4 MB
    off += (size_t)32 * 16 * 3136 * 4;
    float* scale = (float*)(ws + off);        // 256 fp32
    off += 256 * 4;
    int* nneg = (int*)(ws + off);             // 256 int
    off += 256 * 4;
    int* negidx = (int*)(ws + off);           // 256*2304 int = 2.4 MB

    stage1<<<dim3(1824), 256, 0, stream>>>(x, (f32x4*)u16, w, scale, nneg, negidx);
    boxbcast<<<dim3(1792), 256, 0, stream>>>(u16, scale, nneg, negidx, x, out);
}

// Round 5
// 180.629 us; speedup vs baseline: 1.0201x; 1.0160x over previous
//
#include <hip/hip_runtime.h>
#include <stdint.h>

// ---------------------------------------------------------------------------
// HardBinaryConv, algebraic form.
//   sign(w) = 1 - 2*[w <= 0]   (reference: 2*(w>0)-1)
//   y[n,o,h,w] = scale[o] * T[n,h,w]
//              - 2*scale[o] * sum_{(i,r,s): w[o,i,r,s]<=0} x[n,i,h+r-1,w+s-1]
//   T[n,h,w]   = sum_{r,s} U[n,h+r-1,w+s-1]   (3x3 box, zero-pad)
//   U[n,h,w]   = sum_i x[n,i,h,w]             (channel sum)
// Correction set is empty for uniform*1e-3 weights but handled exactly.
// Traffic floor: read x (103 MB) + write y (103 MB) ~= 31 us at 6.7 TB/s.
//
// R3 post-mortem: fused box+broadcast was slow because u16[n][g][hw] makes
// the halo reduce a 3136-float-stride gather: 16x 64B-line over-fetch =
// 616 MB of L2 traffic. R4: cooperative launch is not graph-capturable
// (silent no-op) and ws is re-poisoned per iteration (no manual barriers).
//
// This version (2 dispatches):
//   stage1t: x -> u16T[n][hw][g]  (g innermost, transposed through padded
//            LDS; one coalesced f32x4 store per thread) + weight prep.
//   boxbcast: per (n, 4-row stripe, o-group of 32): halo reduce reads
//            CONTIGUOUS 64B/pixel (21.5 KB/block, zero over-fetch), 3x3 box
//            in LDS, then 32 planes x 56 f32x4 NT stores. 3584 blocks.
// ---------------------------------------------------------------------------

typedef float f32x4 __attribute__((ext_vector_type(4)));

// Stage 1, role A (blocks 0..1567): 16-channel partial sums, transposed.
//   block = (n, tile of 16 f32x4-columns); thread (g = t>>4, sl = t&15).
//   u16T layout: [n][hw=3136][g=16] floats (64 B per pixel, g innermost).
// Stage 1, role B (blocks 1568..1823): scale[o] = mean|w[o]| + sparse list
// of non-positive weights (block o-1568 owns nneg[o]).
__global__ __launch_bounds__(256) void stage1t(const float* __restrict__ x,
                                               float* __restrict__ u16T,
                                               const float* __restrict__ w,
                                               float* __restrict__ scale,
                                               int* __restrict__ nneg,
                                               int* __restrict__ negidx) {
    __shared__ float Ls[64][17];             // 64 hw x 16 g, +1 pad
    __shared__ float red[4];
    __shared__ int cnt;
    const int t = threadIdx.x;
    if (blockIdx.x < 1568) {
        const int b    = blockIdx.x;
        const int n    = b / 49;
        const int tile = b - n * 49;         // 49 tiles * 16 f32x4 = 784
        const int g    = t >> 4;             // 0..15
        const int sl   = t & 15;             // 0..15
        const int hw4  = tile * 16 + sl;
        const f32x4* xp =
            (const f32x4*)(x + (size_t)(n * 256 + g * 16) * 3136) + hw4;
        f32x4 s = {0.f, 0.f, 0.f, 0.f};
#pragma unroll
        for (int c = 0; c < 16; ++c)         // 784 f32x4 = one 3136-elem plane
            s += __builtin_nontemporal_load(xp + c * 784);
        // transpose: Ls[hw_local][g]
        const int r0 = sl * 4;
        Ls[r0 + 0][g] = s.x;
        Ls[r0 + 1][g] = s.y;
        Ls[r0 + 2][g] = s.z;
        Ls[r0 + 3][g] = s.w;
        __syncthreads();
        // coalesced f32x4 store: thread t covers (hw_local = t/4, g = (t%4)*4..+3)
        const int hwl = t >> 2, gb = (t & 3) * 4;
        f32x4 o = {Ls[hwl][gb], Ls[hwl][gb + 1], Ls[hwl][gb + 2], Ls[hwl][gb + 3]};
        f32x4* dst = (f32x4*)(u16T + (size_t)n * 50176 + (size_t)tile * 1024);
        dst[t] = o;                          // plain store: L2/L3-resident
    } else {
        const int o = blockIdx.x - 1568;
        if (t == 0) cnt = 0;
        __syncthreads();
        const float* wp = w + ((size_t)o * 256 + t) * 9;
        float s = 0.f;
#pragma unroll
        for (int k = 0; k < 9; ++k) {
            const float v = wp[k];
            s += fabsf(v);
            if (v <= 0.f) {                  // sign would be -1 here (rare)
                const int slot = atomicAdd(&cnt, 1);
                negidx[o * 2304 + slot] = t * 9 + k;
            }
        }
#pragma unroll
        for (int off = 32; off > 0; off >>= 1) s += __shfl_down(s, off);
        if ((t & 63) == 0) red[t >> 6] = s;
        __syncthreads();
        if (t == 0) {
            scale[o] = (red[0] + red[1] + red[2] + red[3]) * (1.f / 2304.f);
            nneg[o]  = cnt;
        }
    }
}

// Stage 2: fused {16-group reduce (contiguous) + 3x3 box + 32-plane bcast}.
// grid 3584 = 32 n * 14 stripes (4 rows) * 8 o-groups (32 o each).
// Per block: 21.5 KB contiguous halo reads (L2/L3, zero over-fetch) ->
// T stripe (224 f) in LDS -> 32 planes * 56 f32x4 NT stores (28.7 KB).
__global__ __launch_bounds__(256) void boxbcast(const float* __restrict__ u16T,
                                                const float* __restrict__ scale,
                                                const int* __restrict__ nneg,
                                                const int* __restrict__ negidx,
                                                const float* __restrict__ x,
                                                float* __restrict__ out) {
    __shared__ float Us[336];                // 6 rows x 56 (halo)
    __shared__ float Tls[224];               // 4 rows x 56
    __shared__ float ssc[32];
    __shared__ int   snn[32];
    const int b  = blockIdx.x;
    const int og = b & 7;                    // o-group: 32 planes
    const int ns = b >> 3;
    const int n  = ns / 14;
    const int st = ns - n * 14;
    const int h0 = st * 4;
    const int t  = threadIdx.x;

    if (t < 32) {                            // stage per-o constants
        ssc[t] = scale[og * 32 + t];
        snn[t] = nneg[og * 32 + t];
    }

    const float* baseT = u16T + (size_t)n * 50176;
    for (int idx = t; idx < 336; idx += 256) {
        const int lr = idx / 56, col = idx - lr * 56;
        const int h = h0 - 1 + lr;
        float s = 0.f;
        if (h >= 0 && h < 56) {
            const f32x4* p = (const f32x4*)(baseT + (size_t)(h * 56 + col) * 16);
            f32x4 a = p[0] + p[1] + p[2] + p[3];   // 16 contiguous floats
            s = a.x + a.y + a.z + a.w;
        }
        Us[idx] = s;
    }
    __syncthreads();
    if (t < 224) {
        const int lr = t / 56, ww = t - lr * 56;
        float acc = 0.f;
#pragma unroll
        for (int r = 0; r < 3; ++r) {
            const float* row = Us + (lr + r) * 56;
            if (ww > 0)  acc += row[ww - 1];
            acc += row[ww];
            if (ww < 55) acc += row[ww + 1];
        }
        Tls[t] = acc;
    }
    __syncthreads();

    const f32x4* T4 = (const f32x4*)Tls;     // 56 f32x4 per stripe
    float* nb = out + ((size_t)n * 256 + og * 32) * 3136 + h0 * 56;
#pragma unroll
    for (int i = 0; i < 7; ++i) {            // 1792 = 32 planes * 56 f32x4
        const int u   = t + i * 256;
        const int ol  = u / 56;
        const int hw4 = u - ol * 56;
        const float sc = ssc[ol];
        f32x4 v = T4[hw4] * sc;
        const int nn = snn[ol];
        if (nn > 0) {                        // exact sparse correction (rare)
            const float c2 = 2.f * sc;
            for (int q = 0; q < nn; ++q) {
                const int iof = negidx[(og * 32 + ol) * 2304 + q];
                const int ic = iof / 9, rs = iof - ic * 9;
                const int r = rs / 3 - 1, s2 = rs - (rs / 3) * 3 - 1;
                const float* xpl = x + ((size_t)n * 256 + ic) * 3136;
#pragma unroll
                for (int e = 0; e < 4; ++e) {
                    const int p = hw4 * 4 + e;
                    const int lr = p / 56, ww = p - lr * 56;
                    const int hh = h0 + lr + r, w2 = ww + s2;
                    const float xv = (hh >= 0 && hh < 56 && w2 >= 0 && w2 < 56)
                                         ? xpl[hh * 56 + w2] : 0.f;
                    v[e] -= c2 * xv;
                }
            }
        }
        __builtin_nontemporal_store(v, (f32x4*)(nb + (size_t)ol * 3136) + hw4);
    }
}

// ---------------------------------------------------------------------------
extern "C" void kernel_launch(void* const* d_in, const int* in_sizes, int n_in,
                              void* d_out, int out_size, void* d_ws, size_t ws_size,
                              hipStream_t stream) {
    const float* x = (const float*)d_in[0];   // (32,256,56,56) fp32, 103 MB
    const float* w = (const float*)d_in[1];   // (256,256,3,3) fp32, 2.4 MB
    float* out = (float*)d_out;               // (32,256,56,56) fp32, 103 MB

    char* ws = (char*)d_ws;
    size_t off = 0;
    float* u16T = (float*)(ws + off);         // 32*3136*16 fp32 = 6.4 MB
    off += (size_t)32 * 3136 * 16 * 4;
    float* scale = (float*)(ws + off);        // 256 fp32
    off += 256 * 4;
    int* nneg = (int*)(ws + off);             // 256 int
    off += 256 * 4;
    int* negidx = (int*)(ws + off);           // 256*2304 int = 2.4 MB

    stage1t<<<dim3(1824), 256, 0, stream>>>(x, u16T, w, scale, nneg, negidx);
    boxbcast<<<dim3(3584), 256, 0, stream>>>(u16T, scale, nneg, negidx, x, out);
}

// Round 6
// 176.191 us; speedup vs baseline: 1.0458x; 1.0252x over previous
//
#include <hip/hip_runtime.h>
#include <stdint.h>

// ---------------------------------------------------------------------------
// HardBinaryConv, algebraic form.
//   sign(w) = 1 - 2*[w <= 0]   (reference: 2*(w>0)-1)
//   y[n,o,h,w] = scale[o] * T[n,h,w]
//              - 2*scale[o] * sum_{(i,r,s): w[o,i,r,s]<=0} x[n,i,h+r-1,w+s-1]
//   T[n,h,w]   = sum_{r,s} U[n,h+r-1,w+s-1]   (3x3 box, zero-pad)
//   U[n,h,w]   = sum_i x[n,i,h,w]             (channel sum)
// Correction set is empty for uniform*1e-3 weights but handled exactly.
// Traffic floor: read x (103 MB) + write y (103 MB) ~= 33 us at 6.3 TB/s.
//
// Structure lessons (R2/R3/R5): T-compute must be SPLIT from the 103-MB
// broadcast kernel (fused versions lose 4-6 us to redundant preludes);
// cooperative launch is not graph-capturable (R4).
// This version: R1's proven 3-dispatch skeleton, but stage1 LDS-reduces its
// 16 group-partials and emits U (401 KB) directly -- the 6.4-MB u16
// intermediate and boxsum's 16-way strided 64B-line over-fetch (~154 MB of
// L2 traffic) are deleted. boxsum now reads 1.3 KB/block, contiguous.
// ---------------------------------------------------------------------------

typedef float f32x4 __attribute__((ext_vector_type(4)));

// Stage 1, role A (blocks 0..1567): full 256-channel sums -> U[n][3136].
//   block = (n, tile of 16 f32x4 pixels); thread (g = t>>4, sl = t&15) sums
//   its 16-channel group with NT f32x4 loads (same pattern as prior rounds),
//   then a 4-KB LDS reduce collapses the 16 groups; threads 0..63 store one
//   float each (256 B coalesced).
// Stage 1, role B (blocks 1568..1823): scale[o] = mean|w[o]| + sparse list
// of non-positive weights (block o-1568 owns nneg[o]; no pre-zero needed).
__global__ __launch_bounds__(256) void stage1U(const float* __restrict__ x,
                                               float* __restrict__ U,
                                               const float* __restrict__ w,
                                               float* __restrict__ scale,
                                               int* __restrict__ nneg,
                                               int* __restrict__ negidx) {
    __shared__ float Ls[16][64];             // [g][pixel-float]; f32x4 writes
    __shared__ float red[4];                 // are 2-way bank aliased = free
    __shared__ int cnt;
    const int t = threadIdx.x;
    if (blockIdx.x < 1568) {
        const int b    = blockIdx.x;
        const int n    = b / 49;
        const int tile = b - n * 49;         // 49 tiles * 16 f32x4 = 784
        const int g    = t >> 4;             // 0..15 channel group
        const int sl   = t & 15;             // 0..15 pixel slot
        const int hw4  = tile * 16 + sl;
        const f32x4* xp =
            (const f32x4*)(x + (size_t)(n * 256 + g * 16) * 3136) + hw4;
        f32x4 s = {0.f, 0.f, 0.f, 0.f};
#pragma unroll
        for (int c = 0; c < 16; ++c)         // 784 f32x4 = one 3136-elem plane
            s += __builtin_nontemporal_load(xp + c * 784);
        *(f32x4*)&Ls[g][sl * 4] = s;
        __syncthreads();
        if (t < 64) {                        // column sum over 16 groups
            float us = 0.f;
#pragma unroll
            for (int g2 = 0; g2 < 16; ++g2) us += Ls[g2][t];
            U[(size_t)n * 3136 + tile * 64 + t] = us;  // 256 B coalesced
        }
    } else {
        const int o = blockIdx.x - 1568;
        if (t == 0) cnt = 0;
        __syncthreads();
        const float* wp = w + ((size_t)o * 256 + t) * 9;
        float s = 0.f;
#pragma unroll
        for (int k = 0; k < 9; ++k) {
            const float v = wp[k];
            s += fabsf(v);
            if (v <= 0.f) {                  // sign would be -1 here (rare)
                const int slot = atomicAdd(&cnt, 1);
                negidx[o * 2304 + slot] = t * 9 + k;
            }
        }
#pragma unroll
        for (int off = 32; off > 0; off >>= 1) s += __shfl_down(s, off);
        if ((t & 63) == 0) red[t >> 6] = s;
        __syncthreads();
        if (t == 0) {
            scale[o] = (red[0] + red[1] + red[2] + red[3]) * (1.f / 2304.f);
            nneg[o]  = cnt;
        }
    }
}

// Stage 2: 3x3 zero-padded box filter on U -> T.  grid 448 = 32 n * 14
// 4-row stripes; reads 336 contiguous-row floats (1.3 KB) per block.
__global__ __launch_bounds__(256) void boxsumU(const float* __restrict__ U,
                                               float* __restrict__ T) {
    __shared__ float Us[336];                // 6 rows x 56 (halo)
    const int n  = blockIdx.x / 14;
    const int h0 = (blockIdx.x - n * 14) * 4;
    const int t  = threadIdx.x;
    const float* Un = U + (size_t)n * 3136;
    for (int idx = t; idx < 336; idx += 256) {
        const int lr = idx / 56, col = idx - lr * 56;
        const int h = h0 - 1 + lr;
        Us[idx] = (h >= 0 && h < 56) ? Un[h * 56 + col] : 0.f;
    }
    __syncthreads();
    if (t < 224) {
        const int lr = t / 56, ww = t - lr * 56;
        float acc = 0.f;
#pragma unroll
        for (int r = 0; r < 3; ++r) {
            const float* row = Us + (lr + r) * 56;
            if (ww > 0)  acc += row[ww - 1];
            acc += row[ww];
            if (ww < 55) acc += row[ww + 1];
        }
        T[(size_t)n * 3136 + (h0 + lr) * 56 + ww] = acc;
    }
}

// Stage 3: broadcast scale[o]*T into each (n,o) output plane (+ correction).
// grid 8192 = n*256+o (o fastest => T[n] L2-resident across 256 blocks).
// NT stores: y is written once, never re-read -> don't flush L2 with it.
__global__ __launch_bounds__(256) void yout(const float* __restrict__ T,
                                            const float* __restrict__ scale,
                                            const int* __restrict__ nneg,
                                            const int* __restrict__ negidx,
                                            const float* __restrict__ x,
                                            float* __restrict__ out) {
    const int b = blockIdx.x;
    const int o = b & 255, n = b >> 8;
    const float sc = scale[o];
    const f32x4* Tn = (const f32x4*)(T + (size_t)n * 3136);
    f32x4* op = (f32x4*)(out + ((size_t)n * 256 + o) * 3136);
    if (nneg[o] == 0) {                      // uniform fast path
#pragma unroll
        for (int j = 0; j < 4; ++j) {
            const int hw4 = threadIdx.x + j * 256;
            if (hw4 >= 784) break;           // 784 f32x4 = 3136 floats
            f32x4 v = Tn[hw4] * sc;
            __builtin_nontemporal_store(v, op + hw4);
        }
    } else {                                 // exact sparse correction (rare)
        const int nn = nneg[o];
        const float c2 = 2.f * sc;
#pragma unroll
        for (int j = 0; j < 4; ++j) {
            const int hw4 = threadIdx.x + j * 256;
            if (hw4 >= 784) break;
            f32x4 v = Tn[hw4] * sc;
            for (int q = 0; q < nn; ++q) {
                const int iof = negidx[o * 2304 + q];
                const int i = iof / 9, rs = iof - i * 9;
                const int r = rs / 3 - 1, s2 = rs - (rs / 3) * 3 - 1;
                const float* xpl = x + ((size_t)n * 256 + i) * 3136;
#pragma unroll
                for (int e = 0; e < 4; ++e) {
                    const int p = hw4 * 4 + e;
                    const int h = p / 56 + r, ww = p - (p / 56) * 56 + s2;
                    const float xv = (h >= 0 && h < 56 && ww >= 0 && ww < 56)
                                         ? xpl[h * 56 + ww] : 0.f;
                    v[e] -= c2 * xv;
                }
            }
            __builtin_nontemporal_store(v, op + hw4);
        }
    }
}

// ---------------------------------------------------------------------------
extern "C" void kernel_launch(void* const* d_in, const int* in_sizes, int n_in,
                              void* d_out, int out_size, void* d_ws, size_t ws_size,
                              hipStream_t stream) {
    const float* x = (const float*)d_in[0];   // (32,256,56,56) fp32, 103 MB
    const float* w = (const float*)d_in[1];   // (256,256,3,3) fp32, 2.4 MB
    float* out = (float*)d_out;               // (32,256,56,56) fp32, 103 MB

    char* ws = (char*)d_ws;
    size_t off = 0;
    float* U = (float*)(ws + off);            // 32*3136 fp32 = 401 KB
    off += (size_t)32 * 3136 * 4;
    float* T = (float*)(ws + off);            // 32*3136 fp32 = 401 KB
    off += (size_t)32 * 3136 * 4;
    float* scale = (float*)(ws + off);        // 256 fp32
    off += 256 * 4;
    int* nneg = (int*)(ws + off);             // 256 int
    off += 256 * 4;
    int* negidx = (int*)(ws + off);           // 256*2304 int = 2.4 MB

    stage1U<<<dim3(1824), 256, 0, stream>>>(x, U, w, scale, nneg, negidx);
    boxsumU<<<dim3(448), 256, 0, stream>>>(U, T);
    yout<<<dim3(8192), 256, 0, stream>>>(T, scale, nneg, negidx, x, out);
}